// Round 9
// baseline (2386.916 us; speedup 1.0000x reference)
//
#include <hip/hip_runtime.h>
#include <hip/hip_bf16.h>

// Texture_trans: patch-correlation texture transfer + residual conv stack.
// B=4, H=W=64, L=4096, C=64.
// ALL inputs/outputs are FLOAT32 (per reference: jax.random.normal(..., jnp.float32)).
// Prior rounds misread buffers as bf16 -> mantissa halves decoded as bf16 NaN/Inf.
// fp32 math throughout; scalar corr (no MFMA); no guards/fallbacks.
// Workspace: 12,976,128 B. Dead-code: residual blocks 0..2 never affect output.

#define BATCH 4

// ---------------- K1: per-pixel channel sum-of-squares from NLC fp32
__global__ __launch_bounds__(256) void prep_ss(const float* __restrict__ c0,
    const float* __restrict__ c1, float* __restrict__ ss0, float* __restrict__ ss1)
{
  int tid = blockIdx.x * 256 + threadIdx.x;          // b*4096 + l, grid 64
  const float* p0 = c0 + (size_t)tid * 64;
  const float* p1 = c1 + (size_t)tid * 64;
  float s0 = 0.f, s1 = 0.f;
  for (int c = 0; c < 64; ++c) {
    float a = p0[c]; s0 += a * a;
    float b = p1[c]; s1 += b * b;
  }
  ss0[tid] = s0;
  ss1[tid] = s1;
}

// ---------------- K2: 3x3 box-sum of sumsq -> 1/max(patch_norm, EPS)
__global__ __launch_bounds__(256) void norm_kernel(const float* __restrict__ ss0,
    const float* __restrict__ ss1, float* __restrict__ inv0, float* __restrict__ inv1)
{
  int tid = blockIdx.x * 256 + threadIdx.x;
  int b = tid >> 12, l = tid & 4095;
  int y = l >> 6, x = l & 63;
  int base = b << 12;
  float s0 = 0.f, s1 = 0.f;
  for (int dy = -1; dy <= 1; ++dy) {
    int yy = y + dy; if (yy < 0 || yy >= 64) continue;
    for (int dx = -1; dx <= 1; ++dx) {
      int xx = x + dx; if (xx < 0 || xx >= 64) continue;
      int ii = base + (yy << 6) + xx;
      s0 += ss0[ii]; s1 += ss1[ii];
    }
  }
  inv0[tid] = 1.f / fmaxf(sqrtf(s0), 1e-12f);
  inv1[tid] = 1.f / fmaxf(sqrtf(s1), 1e-12f);
}

// ---------------- K3: full-column corr. U[l][m] = sum_{taps,chan} c0[l+d]*c1[m+d] (masked);
// S[m] = max_l inv0[l]*U[l][m] * inv1[m]; arg[m] = first argmax l.
// Grid (mt=128 tiles of 32 cols, B). Block 256 = 8 mgroups(x4m) x 32 lgroups(x4l).
// Each block sweeps all 32 sub-tiles of 128 rows. LDS stride 65 -> conflict-free.
__global__ __launch_bounds__(256) void corr_full(const float* __restrict__ c0g,
    const float* __restrict__ c1g, const float* __restrict__ inv0,
    const float* __restrict__ inv1, float* __restrict__ S, int* __restrict__ argb)
{
  __shared__ float Asc[128 * 65];   // c0 rows (l)
  __shared__ float Bsc[32 * 65];    // c1 rows (m)
  __shared__ float lv[32 * 32];     // [m_local][lgroup]
  __shared__ int   li[32 * 32];
  int mt = blockIdx.x, b = blockIdx.y;
  int t = threadIdx.x;
  const float* A0 = c0g + ((size_t)b << 18);   // [4096][64] fp32 per batch
  const float* B0 = c1g + ((size_t)b << 18);
  const float* inv0b = inv0 + (b << 12);
  int mg = t & 7;     // 8 mgroups x 4 m = 32 cols
  int lg = t >> 3;    // 32 lgroups x 4 l = 128 rows/sub

  float bestv[4] = {-1e30f, -1e30f, -1e30f, -1e30f};
  int   besti[4] = {0, 0, 0, 0};

  for (int sub = 0; sub < 32; ++sub) {
    int row0 = sub << 7;
    float acc[4][4];
#pragma unroll
    for (int j = 0; j < 4; ++j)
#pragma unroll
      for (int mm = 0; mm < 4; ++mm) acc[j][mm] = 0.f;

    for (int r = 0; r < 9; ++r) {            // tap: ki=r/3, kj=r%3
      int ki = r / 3, kj = r - ki * 3;
      __syncthreads();
      // stage A: 128 rows x 16 float4 = 2048 items, 8/thread
#pragma unroll
      for (int i = 0; i < 8; ++i) {
        int idx = t + (i << 8);              // < 2048
        int row = idx >> 4, c4 = (idx & 15) << 2;
        int gl = row0 + row;
        int ty = (gl >> 6) + ki - 1, tx = (gl & 63) + kj - 1;
        float4 v = make_float4(0.f, 0.f, 0.f, 0.f);
        if ((unsigned)ty < 64u && (unsigned)tx < 64u)
          v = *(const float4*)(&A0[(((size_t)(ty << 6) + tx) << 6) + c4]);
        float* dst = &Asc[row * 65 + c4];
        dst[0] = v.x; dst[1] = v.y; dst[2] = v.z; dst[3] = v.w;
      }
      // stage B: 32 rows x 16 float4 = 512 items, 2/thread
#pragma unroll
      for (int i = 0; i < 2; ++i) {
        int idx = t + (i << 8);              // < 512
        int row = idx >> 4, c4 = (idx & 15) << 2;
        int gm = (mt << 5) + row;
        int uy = (gm >> 6) + ki - 1, ux = (gm & 63) + kj - 1;
        float4 v = make_float4(0.f, 0.f, 0.f, 0.f);
        if ((unsigned)uy < 64u && (unsigned)ux < 64u)
          v = *(const float4*)(&B0[(((size_t)(uy << 6) + ux) << 6) + c4]);
        float* dst = &Bsc[row * 65 + c4];
        dst[0] = v.x; dst[1] = v.y; dst[2] = v.z; dst[3] = v.w;
      }
      __syncthreads();
      const float* Ab = &Asc[(lg << 2) * 65];
      const float* Bb = &Bsc[(mg << 2) * 65];
#pragma unroll 8
      for (int k = 0; k < 64; ++k) {
        float b0 = Bb[k], b1 = Bb[65 + k], b2 = Bb[130 + k], b3 = Bb[195 + k];
#pragma unroll
        for (int j = 0; j < 4; ++j) {
          float a = Ab[j * 65 + k];
          acc[j][0] += a * b0; acc[j][1] += a * b1;
          acc[j][2] += a * b2; acc[j][3] += a * b3;
        }
      }
    }
    // fold into running best; l ascending within thread -> strict > keeps first max
#pragma unroll
    for (int j = 0; j < 4; ++j) {
      int l = row0 + (lg << 2) + j;
      float sc = inv0b[l];
#pragma unroll
      for (int mm = 0; mm < 4; ++mm) {
        float v = acc[j][mm] * sc;
        if (v > bestv[mm]) { bestv[mm] = v; besti[mm] = l; }
      }
    }
  }

  __syncthreads();
#pragma unroll
  for (int mm = 0; mm < 4; ++mm) {
    int ml = (mg << 2) + mm;
    lv[ml * 32 + lg] = bestv[mm];
    li[ml * 32 + lg] = besti[mm];
  }
  __syncthreads();
  if (t < 32) {
    float bv = -1e30f; int bi = 0x7FFFFFFF;
    for (int s = 0; s < 32; ++s) {
      float v = lv[t * 32 + s]; int id = li[t * 32 + s];
      if (v > bv || (v == bv && id < bi)) { bv = v; bi = id; }
    }
    int m = (mt << 5) + t;
    S[(b << 12) + m] = bv * inv1[(b << 12) + m];
    argb[(b << 12) + m] = ((unsigned)bi < 4096u) ? bi : 0;
  }
}

// ---------------- K4: T = fold3(gather(f0_unfold, arg))/9 -> NCHW fp32
__global__ __launch_bounds__(256) void tgather_kernel(const float* __restrict__ f0,
    const int* __restrict__ arg, float* __restrict__ T)
{
  __shared__ int a3[192];
  __shared__ float tl[64 * 65];
  int y = blockIdx.x, b = blockIdx.y, t = threadIdx.x;
  if (t < 192) {
    int r = t >> 6, xx = t & 63;
    int yy = y + r - 1;
    a3[t] = (yy >= 0 && yy < 64) ? arg[(b << 12) + (yy << 6) + xx] : 0;
  }
  __syncthreads();
  int c = t & 63, pg = t >> 6;
  for (int it = 0; it < 16; ++it) {
    int px = pg + (it << 2);
    float sum = 0.f;
#pragma unroll
    for (int ki = 0; ki < 3; ++ki) {
      int yn = y + 1 - ki;
      if (yn < 0 || yn >= 64) continue;
#pragma unroll
      for (int kj = 0; kj < 3; ++kj) {
        int xn = px + 1 - kj;
        if (xn < 0 || xn >= 64) continue;
        int p = a3[((2 - ki) << 6) + xn];
        int sy = (p >> 6) + ki - 1, sx = (p & 63) + kj - 1;
        if (sy >= 0 && sy < 64 && sx >= 0 && sx < 64)
          sum += f0[((((size_t)b << 12) + (sy << 6) + sx) << 6) + c];
      }
    }
    tl[px * 65 + c] = sum * (1.f / 9.f);
  }
  __syncthreads();
  for (int i = 0; i < 16; ++i) {
    int idx = t + (i << 8); int cd = idx >> 6, px = idx & 63;
    T[(((size_t)b * 64 + cd) << 12) + (y << 6) + px] = tl[px * 65 + cd];
  }
}

// ---------------- direct conv, fp32. dm=1: stage delta = c1-c0 on the fly from NLC inputs
// (in0=c0 NLC, in1=c1 NLC). dm=0: in0 = NCHW; channels >=64 come from in1 (NCHW, conv5 concat).
// grid (16 y-groups of 4 rows, 16 co-groups of 4, B); block (64 x, 4 rows).
// Weight/bias indices depend only on blockIdx/loop vars -> wave-uniform scalar loads.
template<int KS, int CINCH>
__global__ __launch_bounds__(256) void conv_k(const float* __restrict__ in0,
    const float* __restrict__ in1, const float* __restrict__ wf,
    const float* __restrict__ bias, float* __restrict__ out,
    const float* __restrict__ res, int dorelu, int dm)
{
  constexpr int P = KS / 2;
  constexpr int W2 = 64 + 2 * P;
  constexpr int NR = KS + 3;           // rows staged for 4 output rows
  constexpr int CIN = CINCH * 16;
  __shared__ float in_s[16 * NR * W2];
  int b = blockIdx.z;
  int y0 = blockIdx.x << 2;
  int co0 = blockIdx.y << 2;
  int x = threadIdx.x, ty = threadIdx.y;
  int tid = (ty << 6) + x;
  int y = y0 + ty;
  float acc[4] = {0.f, 0.f, 0.f, 0.f};
  for (int ch = 0; ch < CINCH; ++ch) {
    __syncthreads();
    for (int s = tid; s < 16 * NR * W2; s += 256) {
      int col = s % W2; int rest = s / W2; int r = rest % NR; int ci = rest / NR;
      int yy = y0 - P + r; int xx = col - P;
      float v = 0.f;
      if (yy >= 0 && yy < 64 && xx >= 0 && xx < 64) {
        int cig = (ch << 4) + ci;
        if (dm) {
          size_t ni = ((((size_t)b << 12) + (yy << 6) + xx) << 6) + cig;  // NLC
          v = in1[ni] - in0[ni];                                          // delta = c1-c0
        } else if (cig < 64) {
          v = in0[(((size_t)b * 64 + cig) << 12) + (yy << 6) + xx];
        } else {
          v = in1[(((size_t)b * 64 + (cig - 64)) << 12) + (yy << 6) + xx];
        }
      }
      in_s[s] = v;
    }
    __syncthreads();
    const float* w0 = wf + ((size_t)co0 * CIN + (ch << 4)) * (KS * KS);
    for (int ci = 0; ci < 16; ++ci) {
#pragma unroll
      for (int kh = 0; kh < KS; ++kh) {
        int rbase = (ci * NR + ty + kh) * W2 + x;
#pragma unroll
        for (int kw = 0; kw < KS; ++kw) {
          float iv = in_s[rbase + kw];
#pragma unroll
          for (int j = 0; j < 4; ++j)
            acc[j] += iv * w0[(size_t)j * CIN * KS * KS + ci * KS * KS + kh * KS + kw];
        }
      }
    }
  }
#pragma unroll
  for (int j = 0; j < 4; ++j) {
    int co = co0 + j;
    float v = acc[j] + bias[co];
    if (dorelu) v = fmaxf(v, 0.f);
    size_t oi = (((size_t)b * 64 + co) << 12) + (y << 6) + x;
    if (res) v += res[oi];
    out[oi] = v;
  }
}

// ---------------- K6: out[b,l,c] = dcf + xs*S, NCHW -> NLC transpose, fp32 store
__global__ __launch_bounds__(256) void final_kernel(const float* __restrict__ dcf,
    const float* __restrict__ xs, const float* __restrict__ S, float* __restrict__ out)
{
  __shared__ float tl[64 * 65];
  int lt = blockIdx.x, b = blockIdx.y, t = threadIdx.x;
  int l0 = lt << 6;
  for (int i = 0; i < 16; ++i) {
    int idx = t + (i << 8); int cd = idx >> 6, lx = idx & 63;
    size_t gi = (((size_t)b * 64 + cd) << 12) + l0 + lx;
    tl[lx * 65 + cd] = dcf[gi] + xs[gi] * S[(b << 12) + l0 + lx];
  }
  __syncthreads();
  for (int i = 0; i < 16; ++i) {
    int idx = t + (i << 8); int lx = idx >> 6, cd = idx & 63;
    out[((((size_t)b << 12) + l0 + lx) << 6) + cd] = tl[lx * 65 + cd];
  }
}

extern "C" void kernel_launch(void* const* d_in, const int* in_sizes, int n_in,
                              void* d_out, int out_size, void* d_ws, size_t ws_size,
                              hipStream_t stream)
{
  (void)in_sizes; (void)n_in; (void)out_size; (void)ws_size;
  const float* c0     = (const float*)d_in[0];
  const float* f0     = (const float*)d_in[1];
  const float* c1     = (const float*)d_in[2];
  const float* head_w = (const float*)d_in[3];
  const float* head_b = (const float*)d_in[4];
  const float* rb_w1  = (const float*)d_in[5];
  const float* rb_b1  = (const float*)d_in[6];
  const float* rb_w2  = (const float*)d_in[7];
  const float* rb_b2  = (const float*)d_in[8];
  const float* tail_w = (const float*)d_in[9];
  const float* tail_b = (const float*)d_in[10];
  const float* sq_w   = (const float*)d_in[11];
  const float* sq_b   = (const float*)d_in[12];
  float* out = (float*)d_out;
  char* ws = (char*)d_ws;

  // ---- workspace layout: 12,976,128 B, lifetime-aliased slots ----
  const size_t OFF_SS0  = 0;          // 64 KB
  const size_t OFF_SS1  = 65536;      // 64 KB
  const size_t OFF_INV0 = 131072;     // 64 KB
  const size_t OFF_INV1 = 196608;     // 64 KB
  const size_t OFF_S    = 262144;     // 64 KB
  const size_t OFF_ARG  = 327680;     // 64 KB
  const size_t OFF_S1   = 393216;     // 4 MB fp32: xb -> xs
  const size_t OFF_S2   = 4587520;    // 4 MB fp32: x1 -> T
  const size_t OFF_S3   = 8781824;    // 4 MB fp32: h -> dcf
                                      // end = 12,976,128

  float* ss0  = (float*)(ws + OFF_SS0);
  float* ss1  = (float*)(ws + OFF_SS1);
  float* inv0 = (float*)(ws + OFF_INV0);
  float* inv1 = (float*)(ws + OFF_INV1);
  float* Sbuf = (float*)(ws + OFF_S);
  int*   argb = (int*)(ws + OFF_ARG);
  float* xb   = (float*)(ws + OFF_S1);
  float* xsb  = (float*)(ws + OFF_S1);   // xb dead after conv4
  float* x1   = (float*)(ws + OFF_S2);
  float* Tb   = (float*)(ws + OFF_S2);   // x1 dead after conv4 (tgather runs after)
  float* hb   = (float*)(ws + OFF_S3);
  float* dcf  = (float*)(ws + OFF_S3);   // h dead after conv3

  dim3 b256(256);
  prep_ss<<<dim3(64), b256, 0, stream>>>(c0, c1, ss0, ss1);
  norm_kernel<<<dim3(64), b256, 0, stream>>>(ss0, ss1, inv0, inv1);
  corr_full<<<dim3(128, BATCH), b256, 0, stream>>>(c0, c1, inv0, inv1, Sbuf, argb);

  // conv stack (only residual block 3 affects the output — x is rebuilt from x1 each iter)
  dim3 cgrid(16, 16, BATCH), cblk(64, 4);
  conv_k<5, 4><<<cgrid, cblk, 0, stream>>>(c0, c1, head_w, head_b, x1, nullptr, 0, 1);  // delta on the fly
  conv_k<3, 4><<<cgrid, cblk, 0, stream>>>(x1, nullptr, rb_w1 + 110592, rb_b1 + 192, hb, nullptr, 1, 0);
  conv_k<3, 4><<<cgrid, cblk, 0, stream>>>(hb, nullptr, rb_w2 + 110592, rb_b2 + 192, xb, x1, 0, 0);
  conv_k<5, 4><<<cgrid, cblk, 0, stream>>>(xb, nullptr, tail_w, tail_b, dcf, x1, 0, 0);

  tgather_kernel<<<dim3(64, BATCH), b256, 0, stream>>>(f0, argb, Tb);   // into x1's slot (x1 dead)
  conv_k<5, 8><<<cgrid, cblk, 0, stream>>>(dcf, Tb, sq_w, sq_b, xsb, nullptr, 0, 0);

  final_kernel<<<dim3(64, BATCH), b256, 0, stream>>>(dcf, xsb, Sbuf, out);
}

// Round 11
// 1146.984 us; speedup vs baseline: 2.0810x; 2.0810x over previous
//
#include <hip/hip_runtime.h>
#include <hip/hip_bf16.h>

// Texture_trans: patch-correlation texture transfer + residual conv stack.
// B=4, H=W=64, L=4096, C=64. ALL inputs/outputs fp32.
// R11: fix R10's staging bug — only 16 of 32 K-channels were staged per phase
// (1024 items instead of 2048); LDS entries 16..31 per row were stale garbage.
// C/D layout (HW-verified m89/m91): col = lane&15 (B-row), row = (lane>>4)*4+reg (A-row).
// Workspace: 14,024,704 B. hi/lo arrays alias conv slots S1/S3 (dead until after corr).

#define BATCH 4

typedef unsigned short u16;
typedef __attribute__((ext_vector_type(8))) short short8;
typedef __attribute__((ext_vector_type(4))) float f32x4;

// ---------------- K1: per-pixel channel sum-of-squares from NLC fp32
__global__ __launch_bounds__(256) void prep_ss(const float* __restrict__ c0,
    const float* __restrict__ c1, float* __restrict__ ss0, float* __restrict__ ss1)
{
  int tid = blockIdx.x * 256 + threadIdx.x;          // b*4096 + l, grid 64
  const float* p0 = c0 + (size_t)tid * 64;
  const float* p1 = c1 + (size_t)tid * 64;
  float s0 = 0.f, s1 = 0.f;
  for (int c = 0; c < 64; ++c) {
    float a = p0[c]; s0 += a * a;
    float b = p1[c]; s1 += b * b;
  }
  ss0[tid] = s0;
  ss1[tid] = s1;
}

// ---------------- K2: 3x3 box-sum of sumsq -> 1/max(patch_norm, EPS)
__global__ __launch_bounds__(256) void norm_kernel(const float* __restrict__ ss0,
    const float* __restrict__ ss1, float* __restrict__ inv0, float* __restrict__ inv1)
{
  int tid = blockIdx.x * 256 + threadIdx.x;
  int b = tid >> 12, l = tid & 4095;
  int y = l >> 6, x = l & 63;
  int base = b << 12;
  float s0 = 0.f, s1 = 0.f;
  for (int dy = -1; dy <= 1; ++dy) {
    int yy = y + dy; if (yy < 0 || yy >= 64) continue;
    for (int dx = -1; dx <= 1; ++dx) {
      int xx = x + dx; if (xx < 0 || xx >= 64) continue;
      int ii = base + (yy << 6) + xx;
      s0 += ss0[ii]; s1 += ss1[ii];
    }
  }
  inv0[tid] = 1.f / fmaxf(sqrtf(s0), 1e-12f);
  inv1[tid] = 1.f / fmaxf(sqrtf(s1), 1e-12f);
}

// ---------------- K3: split fp32 -> bf16 hi + bf16 lo (x ~= hi + lo, err ~2^-18 |x|)
__global__ __launch_bounds__(256) void split_kernel(const float* __restrict__ c0,
    const float* __restrict__ c1, u16* __restrict__ c0h, u16* __restrict__ c0l,
    u16* __restrict__ c1h, u16* __restrict__ c1l)
{
  int i = blockIdx.x * 256 + threadIdx.x;            // grid 4096 -> 1,048,576
  float x = c0[i];
  __hip_bfloat16 h = __float2bfloat16(x);
  float r = x - __bfloat162float(h);
  __hip_bfloat16 lo = __float2bfloat16(r);
  c0h[i] = *(u16*)&h; c0l[i] = *(u16*)&lo;
  x = c1[i];
  h = __float2bfloat16(x);
  r = x - __bfloat162float(h);
  lo = __float2bfloat16(r);
  c1h[i] = *(u16*)&h; c1l[i] = *(u16*)&lo;
}

// ---------------- K4: MFMA corr. U[l][m] = sum_{taps,chan} c0[l+d]*c1[m+d] via
// ah*bh + ah*bl + al*bh (bf16 hi/lo). Running max/argmax of inv0[l]*U over 512-row
// supertiles. Grid (mt=32 col-tiles of 128, lt=8 supertiles, B); 4 sub-tiles of 128 rows;
// per sub-tile 9 taps x 2 half-chunks (K=32 chans). Tile 128x128, 4 waves (2x2 of 64x64).
__global__ __launch_bounds__(256) void corr_mfma(const u16* __restrict__ c0h,
    const u16* __restrict__ c0l, const u16* __restrict__ c1h, const u16* __restrict__ c1l,
    const float* __restrict__ inv0, float* __restrict__ pval, int* __restrict__ pidx)
{
  __shared__ __align__(16) u16 Ah[128 * 40];   // stride 40 u16 = 80 B: 2-way-only conflicts
  __shared__ __align__(16) u16 Al[128 * 40];
  __shared__ __align__(16) u16 Bh[128 * 40];
  __shared__ __align__(16) u16 Bl[128 * 40];
  __shared__ float lval[128 * 8];
  __shared__ int   lidx[128 * 8];
  int mt = blockIdx.x, lt = blockIdx.y, b = blockIdx.z;
  int t = threadIdx.x;
  const size_t boff = (size_t)b << 18;         // b*4096*64
  const u16* A0h = c0h + boff; const u16* A0l = c0l + boff;
  const u16* B0h = c1h + boff; const u16* B0l = c1l + boff;
  const float* inv0b = inv0 + (b << 12);
  int lane = t & 63, w = t >> 6;
  int wl = w >> 1, wm = w & 1;
  int cc = lane & 15, q = lane >> 4;

  float bval[4] = {-1e30f, -1e30f, -1e30f, -1e30f};
  int   bidx[4] = {0, 0, 0, 0};

  for (int sub = 0; sub < 4; ++sub) {
    int row0 = (lt << 9) + (sub << 7);
    f32x4 acc[4][4];
#pragma unroll
    for (int i = 0; i < 4; ++i)
#pragma unroll
      for (int j = 0; j < 4; ++j) acc[i][j] = (f32x4){0.f, 0.f, 0.f, 0.f};

    for (int ph = 0; ph < 18; ++ph) {          // tap r = ph/2, half h = ph&1
      int r = ph >> 1, hh = ph & 1;
      int ki = r / 3, kj = r - ki * 3;
      __syncthreads();
      // stage 4 matrices x 128 rows x 4 uint4 (32 chans) = 2048 items, 8/thread
#pragma unroll
      for (int i = 0; i < 8; ++i) {
        int idx = t + (i << 8);                // < 2048
        int mat = idx >> 9;                    // 0=Ah 1=Al 2=Bh 3=Bl
        int rem = idx & 511;
        int row = rem >> 2, cs = rem & 3;      // cs: which uint4 (8 chans), 4/row = 32 chans
        int isB = mat >> 1;
        int g = (isB ? (mt << 7) : row0) + row;
        int ty = (g >> 6) + ki - 1, tx = (g & 63) + kj - 1;
        uint4 v = make_uint4(0u, 0u, 0u, 0u);
        if ((unsigned)ty < 64u && (unsigned)tx < 64u) {
          const u16* src = (mat == 0) ? A0h : (mat == 1) ? A0l : (mat == 2) ? B0h : B0l;
          v = *(const uint4*)(&src[(((size_t)(ty << 6) + tx) << 6) + (hh << 5) + (cs << 3)]);
        }
        u16* dst = (mat == 0) ? Ah : (mat == 1) ? Al : (mat == 2) ? Bh : Bl;
        *(uint4*)(&dst[row * 40 + (cs << 3)]) = v;
      }
      __syncthreads();
      short8 afh[4], afl[4], bfh[4], bfl[4];
#pragma unroll
      for (int i = 0; i < 4; ++i) {
        int ra = ((wl << 6) + (i << 4) + cc) * 40 + (q << 3);
        afh[i] = *(const short8*)(&Ah[ra]);
        afl[i] = *(const short8*)(&Al[ra]);
      }
#pragma unroll
      for (int j = 0; j < 4; ++j) {
        int rb = ((wm << 6) + (j << 4) + cc) * 40 + (q << 3);
        bfh[j] = *(const short8*)(&Bh[rb]);
        bfl[j] = *(const short8*)(&Bl[rb]);
      }
#pragma unroll
      for (int i = 0; i < 4; ++i)
#pragma unroll
        for (int j = 0; j < 4; ++j) {
          acc[i][j] = __builtin_amdgcn_mfma_f32_16x16x32_bf16(afh[i], bfl[j], acc[i][j], 0, 0, 0);
          acc[i][j] = __builtin_amdgcn_mfma_f32_16x16x32_bf16(afl[i], bfh[j], acc[i][j], 0, 0, 0);
          acc[i][j] = __builtin_amdgcn_mfma_f32_16x16x32_bf16(afh[i], bfh[j], acc[i][j], 0, 0, 0);
        }
    }
    // epilogue: row (A-index l) = q*4+reg, col (B-index m) = cc [m89/m91-verified]
#pragma unroll
    for (int i = 0; i < 4; ++i) {
#pragma unroll
      for (int rg = 0; rg < 4; ++rg) {
        int l = row0 + (wl << 6) + (i << 4) + (q << 2) + rg;
        float sc = inv0b[l];
#pragma unroll
        for (int j = 0; j < 4; ++j) {
          float v = acc[i][j][rg] * sc;
          if (v > bval[j]) { bval[j] = v; bidx[j] = l; }  // l ascending -> first max kept
        }
      }
    }
  }

  __syncthreads();
  int slot = (wl << 2) + q;
#pragma unroll
  for (int j = 0; j < 4; ++j) {
    int col = (wm << 6) + (j << 4) + cc;
    lval[col * 8 + slot] = bval[j];
    lidx[col * 8 + slot] = bidx[j];
  }
  __syncthreads();
  if (t < 128) {
    float bv = -1e30f; int bi = 0x7FFFFFFF;
    for (int s = 0; s < 8; ++s) {
      float v = lval[t * 8 + s]; int id = lidx[t * 8 + s];
      if (v > bv || (v == bv && id < bi)) { bv = v; bi = id; }
    }
    size_t o = (size_t)(((b << 3) + lt) << 12) + (mt << 7) + t;
    pval[o] = bv; pidx[o] = bi;
  }
}

// ---------------- K5: reduce 8 supertile partials -> S = max*inv1, argmax (first-max ties)
__global__ __launch_bounds__(256) void reduce_kernel(const float* __restrict__ pval,
    const int* __restrict__ pidx, const float* __restrict__ inv1,
    float* __restrict__ S, int* __restrict__ arg)
{
  int tid = blockIdx.x * 256 + threadIdx.x;  // b*4096 + m
  int b = tid >> 12, m = tid & 4095;
  float bv = -1e30f; int bi = 0x7FFFFFFF;
  for (int lt = 0; lt < 8; ++lt) {
    size_t o = (size_t)(((b << 3) + lt) << 12) + m;
    float v = pval[o]; int id = pidx[o];
    if (v > bv || (v == bv && id < bi)) { bv = v; bi = id; }
  }
  S[tid] = bv * inv1[tid];
  arg[tid] = ((unsigned)bi < 4096u) ? bi : 0;
}

// ---------------- K6: T = fold3(gather(f0_unfold, arg))/9 -> NCHW fp32
__global__ __launch_bounds__(256) void tgather_kernel(const float* __restrict__ f0,
    const int* __restrict__ arg, float* __restrict__ T)
{
  __shared__ int a3[192];
  __shared__ float tl[64 * 65];
  int y = blockIdx.x, b = blockIdx.y, t = threadIdx.x;
  if (t < 192) {
    int r = t >> 6, xx = t & 63;
    int yy = y + r - 1;
    a3[t] = (yy >= 0 && yy < 64) ? arg[(b << 12) + (yy << 6) + xx] : 0;
  }
  __syncthreads();
  int c = t & 63, pg = t >> 6;
  for (int it = 0; it < 16; ++it) {
    int px = pg + (it << 2);
    float sum = 0.f;
#pragma unroll
    for (int ki = 0; ki < 3; ++ki) {
      int yn = y + 1 - ki;
      if (yn < 0 || yn >= 64) continue;
#pragma unroll
      for (int kj = 0; kj < 3; ++kj) {
        int xn = px + 1 - kj;
        if (xn < 0 || xn >= 64) continue;
        int p = a3[((2 - ki) << 6) + xn];
        int sy = (p >> 6) + ki - 1, sx = (p & 63) + kj - 1;
        if (sy >= 0 && sy < 64 && sx >= 0 && sx < 64)
          sum += f0[((((size_t)b << 12) + (sy << 6) + sx) << 6) + c];
      }
    }
    tl[px * 65 + c] = sum * (1.f / 9.f);
  }
  __syncthreads();
  for (int i = 0; i < 16; ++i) {
    int idx = t + (i << 8); int cd = idx >> 6, px = idx & 63;
    T[(((size_t)b * 64 + cd) << 12) + (y << 6) + px] = tl[px * 65 + cd];
  }
}

// ---------------- direct conv, fp32. dm=1: delta = c1-c0 staged on the fly from NLC inputs.
// dm=0: in0 NCHW; channels >=64 from in1 (NCHW, conv5 concat). Weight loads wave-uniform.
template<int KS, int CINCH>
__global__ __launch_bounds__(256) void conv_k(const float* __restrict__ in0,
    const float* __restrict__ in1, const float* __restrict__ wf,
    const float* __restrict__ bias, float* __restrict__ out,
    const float* __restrict__ res, int dorelu, int dm)
{
  constexpr int P = KS / 2;
  constexpr int W2 = 64 + 2 * P;
  constexpr int NR = KS + 3;
  constexpr int CIN = CINCH * 16;
  __shared__ float in_s[16 * NR * W2];
  int b = blockIdx.z;
  int y0 = blockIdx.x << 2;
  int co0 = blockIdx.y << 2;
  int x = threadIdx.x, ty = threadIdx.y;
  int tid = (ty << 6) + x;
  int y = y0 + ty;
  float acc[4] = {0.f, 0.f, 0.f, 0.f};
  for (int ch = 0; ch < CINCH; ++ch) {
    __syncthreads();
    for (int s = tid; s < 16 * NR * W2; s += 256) {
      int col = s % W2; int rest = s / W2; int r = rest % NR; int ci = rest / NR;
      int yy = y0 - P + r; int xx = col - P;
      float v = 0.f;
      if (yy >= 0 && yy < 64 && xx >= 0 && xx < 64) {
        int cig = (ch << 4) + ci;
        if (dm) {
          size_t ni = ((((size_t)b << 12) + (yy << 6) + xx) << 6) + cig;  // NLC
          v = in1[ni] - in0[ni];
        } else if (cig < 64) {
          v = in0[(((size_t)b * 64 + cig) << 12) + (yy << 6) + xx];
        } else {
          v = in1[(((size_t)b * 64 + (cig - 64)) << 12) + (yy << 6) + xx];
        }
      }
      in_s[s] = v;
    }
    __syncthreads();
    const float* w0 = wf + ((size_t)co0 * CIN + (ch << 4)) * (KS * KS);
    for (int ci = 0; ci < 16; ++ci) {
#pragma unroll
      for (int kh = 0; kh < KS; ++kh) {
        int rbase = (ci * NR + ty + kh) * W2 + x;
#pragma unroll
        for (int kw = 0; kw < KS; ++kw) {
          float iv = in_s[rbase + kw];
#pragma unroll
          for (int j = 0; j < 4; ++j)
            acc[j] += iv * w0[(size_t)j * CIN * KS * KS + ci * KS * KS + kh * KS + kw];
        }
      }
    }
  }
#pragma unroll
  for (int j = 0; j < 4; ++j) {
    int co = co0 + j;
    float v = acc[j] + bias[co];
    if (dorelu) v = fmaxf(v, 0.f);
    size_t oi = (((size_t)b * 64 + co) << 12) + (y << 6) + x;
    if (res) v += res[oi];
    out[oi] = v;
  }
}

// ---------------- K8: out[b,l,c] = dcf + xs*S, NCHW -> NLC transpose, fp32 store
__global__ __launch_bounds__(256) void final_kernel(const float* __restrict__ dcf,
    const float* __restrict__ xs, const float* __restrict__ S, float* __restrict__ out)
{
  __shared__ float tl[64 * 65];
  int lt = blockIdx.x, b = blockIdx.y, t = threadIdx.x;
  int l0 = lt << 6;
  for (int i = 0; i < 16; ++i) {
    int idx = t + (i << 8); int cd = idx >> 6, lx = idx & 63;
    size_t gi = (((size_t)b * 64 + cd) << 12) + l0 + lx;
    tl[lx * 65 + cd] = dcf[gi] + xs[gi] * S[(b << 12) + l0 + lx];
  }
  __syncthreads();
  for (int i = 0; i < 16; ++i) {
    int idx = t + (i << 8); int lx = idx >> 6, cd = idx & 63;
    out[((((size_t)b << 12) + l0 + lx) << 6) + cd] = tl[lx * 65 + cd];
  }
}

extern "C" void kernel_launch(void* const* d_in, const int* in_sizes, int n_in,
                              void* d_out, int out_size, void* d_ws, size_t ws_size,
                              hipStream_t stream)
{
  (void)in_sizes; (void)n_in; (void)out_size; (void)ws_size;
  const float* c0     = (const float*)d_in[0];
  const float* f0     = (const float*)d_in[1];
  const float* c1     = (const float*)d_in[2];
  const float* head_w = (const float*)d_in[3];
  const float* head_b = (const float*)d_in[4];
  const float* rb_w1  = (const float*)d_in[5];
  const float* rb_b1  = (const float*)d_in[6];
  const float* rb_w2  = (const float*)d_in[7];
  const float* rb_b2  = (const float*)d_in[8];
  const float* tail_w = (const float*)d_in[9];
  const float* tail_b = (const float*)d_in[10];
  const float* sq_w   = (const float*)d_in[11];
  const float* sq_b   = (const float*)d_in[12];
  float* out = (float*)d_out;
  char* ws = (char*)d_ws;

  // ---- layout: 14,024,704 B. hi/lo (8 MB) alias S1/S3 (dead until after corr) ----
  const size_t OFF_SS0  = 0;
  const size_t OFF_SS1  = 65536;
  const size_t OFF_INV0 = 131072;
  const size_t OFF_INV1 = 196608;
  const size_t OFF_S    = 262144;
  const size_t OFF_ARG  = 327680;
  const size_t OFF_PVAL = 393216;     // 512 KB (B*8*4096 f32)
  const size_t OFF_PIDX = 917504;     // 512 KB
  const size_t OFF_S1   = 1441792;    // 4 MB: c0h(2M)+c0l(2M) -> xb -> xs
  const size_t OFF_S2   = 5636096;    // 4 MB: x1 -> T
  const size_t OFF_S3   = 9830400;    // 4 MB: c1h(2M)+c1l(2M) -> hb -> dcf

  float* ss0  = (float*)(ws + OFF_SS0);
  float* ss1  = (float*)(ws + OFF_SS1);
  float* inv0 = (float*)(ws + OFF_INV0);
  float* inv1 = (float*)(ws + OFF_INV1);
  float* Sbuf = (float*)(ws + OFF_S);
  int*   argb = (int*)(ws + OFF_ARG);
  float* pval = (float*)(ws + OFF_PVAL);
  int*   pidx = (int*)(ws + OFF_PIDX);
  u16*   c0h  = (u16*)(ws + OFF_S1);
  u16*   c0l  = (u16*)(ws + OFF_S1 + 2097152);
  u16*   c1h  = (u16*)(ws + OFF_S3);
  u16*   c1l  = (u16*)(ws + OFF_S3 + 2097152);
  float* xb   = (float*)(ws + OFF_S1);
  float* xsb  = (float*)(ws + OFF_S1);
  float* x1   = (float*)(ws + OFF_S2);
  float* Tb   = (float*)(ws + OFF_S2);
  float* hb   = (float*)(ws + OFF_S3);
  float* dcf  = (float*)(ws + OFF_S3);

  dim3 b256(256);
  prep_ss<<<dim3(64), b256, 0, stream>>>(c0, c1, ss0, ss1);
  norm_kernel<<<dim3(64), b256, 0, stream>>>(ss0, ss1, inv0, inv1);
  split_kernel<<<dim3(4096), b256, 0, stream>>>(c0, c1, c0h, c0l, c1h, c1l);
  corr_mfma<<<dim3(32, 8, BATCH), b256, 0, stream>>>(c0h, c0l, c1h, c1l, inv0, pval, pidx);
  reduce_kernel<<<dim3(64), b256, 0, stream>>>(pval, pidx, inv1, Sbuf, argb);

  // conv stack (only residual block 3 affects output). conv2 (writes S3) and conv3
  // (writes S1) run after corr, which is sequenced above -> hi/lo aliases safe.
  dim3 cgrid(16, 16, BATCH), cblk(64, 4);
  conv_k<5, 4><<<cgrid, cblk, 0, stream>>>(c0, c1, head_w, head_b, x1, nullptr, 0, 1);
  conv_k<3, 4><<<cgrid, cblk, 0, stream>>>(x1, nullptr, rb_w1 + 110592, rb_b1 + 192, hb, nullptr, 1, 0);
  conv_k<3, 4><<<cgrid, cblk, 0, stream>>>(hb, nullptr, rb_w2 + 110592, rb_b2 + 192, xb, x1, 0, 0);
  conv_k<5, 4><<<cgrid, cblk, 0, stream>>>(xb, nullptr, tail_w, tail_b, dcf, x1, 0, 0);

  tgather_kernel<<<dim3(64, BATCH), b256, 0, stream>>>(f0, argb, Tb);   // x1 dead after conv4
  conv_k<5, 8><<<cgrid, cblk, 0, stream>>>(dcf, Tb, sq_w, sq_b, xsb, nullptr, 0, 0);

  final_kernel<<<dim3(64, BATCH), b256, 0, stream>>>(dcf, xsb, Sbuf, out);
}

// Round 12
// 640.463 us; speedup vs baseline: 3.7269x; 1.7909x over previous
//
#include <hip/hip_runtime.h>
#include <hip/hip_bf16.h>

// Texture_trans: patch-correlation texture transfer + residual conv stack.
// B=4, H=W=64, L=4096, C=64. ALL inputs/outputs fp32. Activations NHWC throughout.
// R12: convs -> implicit-GEMM MFMA (bf16 hi/lo 3-term), same verified fragment pattern
// as corr (R11 pass). C/D: col=lane&15 (B=cout), row=(lane>>4)*4+reg (A=pixel).
// Workspace: 15,958,016 B (< proven 16 MiB). 3-slot lifetime aliasing.

#define BATCH 4

typedef unsigned short u16;
typedef unsigned int   u32;
typedef __attribute__((ext_vector_type(8))) short short8;
typedef __attribute__((ext_vector_type(4))) float f32x4;

__device__ __forceinline__ void bsplit2(float a, float b, u32& ho, u32& lo) {
  __hip_bfloat16 ha = __float2bfloat16(a), hb = __float2bfloat16(b);
  float ra = a - __bfloat162float(ha), rb = b - __bfloat162float(hb);
  __hip_bfloat16 la = __float2bfloat16(ra), lb = __float2bfloat16(rb);
  ho = (u32)*(u16*)&ha | ((u32)*(u16*)&hb << 16);
  lo = (u32)*(u16*)&la | ((u32)*(u16*)&lb << 16);
}

// ---------------- K1: per-pixel channel sum-of-squares from NLC fp32
__global__ __launch_bounds__(256) void prep_ss(const float* __restrict__ c0,
    const float* __restrict__ c1, float* __restrict__ ss0, float* __restrict__ ss1)
{
  int tid = blockIdx.x * 256 + threadIdx.x;
  const float* p0 = c0 + (size_t)tid * 64;
  const float* p1 = c1 + (size_t)tid * 64;
  float s0 = 0.f, s1 = 0.f;
  for (int c = 0; c < 64; ++c) {
    float a = p0[c]; s0 += a * a;
    float b = p1[c]; s1 += b * b;
  }
  ss0[tid] = s0;
  ss1[tid] = s1;
}

// ---------------- K2: 3x3 box-sum of sumsq -> 1/max(patch_norm, EPS)
__global__ __launch_bounds__(256) void norm_kernel(const float* __restrict__ ss0,
    const float* __restrict__ ss1, float* __restrict__ inv0, float* __restrict__ inv1)
{
  int tid = blockIdx.x * 256 + threadIdx.x;
  int b = tid >> 12, l = tid & 4095;
  int y = l >> 6, x = l & 63;
  int base = b << 12;
  float s0 = 0.f, s1 = 0.f;
  for (int dy = -1; dy <= 1; ++dy) {
    int yy = y + dy; if (yy < 0 || yy >= 64) continue;
    for (int dx = -1; dx <= 1; ++dx) {
      int xx = x + dx; if (xx < 0 || xx >= 64) continue;
      int ii = base + (yy << 6) + xx;
      s0 += ss0[ii]; s1 += ss1[ii];
    }
  }
  inv0[tid] = 1.f / fmaxf(sqrtf(s0), 1e-12f);
  inv1[tid] = 1.f / fmaxf(sqrtf(s1), 1e-12f);
}

// ---------------- K3: split fp32 -> bf16 hi + lo
__global__ __launch_bounds__(256) void split_kernel(const float* __restrict__ c0,
    const float* __restrict__ c1, u16* __restrict__ c0h, u16* __restrict__ c0l,
    u16* __restrict__ c1h, u16* __restrict__ c1l)
{
  int i = blockIdx.x * 256 + threadIdx.x;
  float x = c0[i];
  __hip_bfloat16 h = __float2bfloat16(x);
  float r = x - __bfloat162float(h);
  __hip_bfloat16 lo = __float2bfloat16(r);
  c0h[i] = *(u16*)&h; c0l[i] = *(u16*)&lo;
  x = c1[i];
  h = __float2bfloat16(x);
  r = x - __bfloat162float(h);
  lo = __float2bfloat16(r);
  c1h[i] = *(u16*)&h; c1l[i] = *(u16*)&lo;
}

// ---------------- K3b: weight transpose+split OIHW fp32 -> [tap][cout][cin] bf16 hi/lo
__global__ __launch_bounds__(256) void wprep(const float* __restrict__ src,
    u16* __restrict__ wh, u16* __restrict__ wl, int Cin, int KK, int n)
{
  int i = blockIdx.x * 256 + threadIdx.x;
  if (i >= n) return;
  int per = Cin * KK;
  int cout = i / per;
  int rem = i - cout * per;
  int cin = rem / KK;
  int tap = rem - cin * KK;
  float x = src[i];
  __hip_bfloat16 h = __float2bfloat16(x);
  float r = x - __bfloat162float(h);
  __hip_bfloat16 lo = __float2bfloat16(r);
  int d = (tap * 64 + cout) * Cin + cin;
  wh[d] = *(u16*)&h;
  wl[d] = *(u16*)&lo;
}

// ---------------- K4: MFMA corr (unchanged from R11 pass)
__global__ __launch_bounds__(256) void corr_mfma(const u16* __restrict__ c0h,
    const u16* __restrict__ c0l, const u16* __restrict__ c1h, const u16* __restrict__ c1l,
    const float* __restrict__ inv0, float* __restrict__ pval, int* __restrict__ pidx)
{
  __shared__ __align__(16) u16 Ah[128 * 40];
  __shared__ __align__(16) u16 Al[128 * 40];
  __shared__ __align__(16) u16 Bh[128 * 40];
  __shared__ __align__(16) u16 Bl[128 * 40];
  __shared__ float lval[128 * 8];
  __shared__ int   lidx[128 * 8];
  int mt = blockIdx.x, lt = blockIdx.y, b = blockIdx.z;
  int t = threadIdx.x;
  const size_t boff = (size_t)b << 18;
  const u16* A0h = c0h + boff; const u16* A0l = c0l + boff;
  const u16* B0h = c1h + boff; const u16* B0l = c1l + boff;
  const float* inv0b = inv0 + (b << 12);
  int lane = t & 63, w = t >> 6;
  int wl = w >> 1, wm = w & 1;
  int cc = lane & 15, q = lane >> 4;

  float bval[4] = {-1e30f, -1e30f, -1e30f, -1e30f};
  int   bidx[4] = {0, 0, 0, 0};

  for (int sub = 0; sub < 4; ++sub) {
    int row0 = (lt << 9) + (sub << 7);
    f32x4 acc[4][4];
#pragma unroll
    for (int i = 0; i < 4; ++i)
#pragma unroll
      for (int j = 0; j < 4; ++j) acc[i][j] = (f32x4){0.f, 0.f, 0.f, 0.f};

    for (int ph = 0; ph < 18; ++ph) {
      int r = ph >> 1, hh = ph & 1;
      int ki = r / 3, kj = r - ki * 3;
      __syncthreads();
#pragma unroll
      for (int i = 0; i < 8; ++i) {
        int idx = t + (i << 8);
        int mat = idx >> 9;
        int rem = idx & 511;
        int row = rem >> 2, cs = rem & 3;
        int isB = mat >> 1;
        int g = (isB ? (mt << 7) : row0) + row;
        int ty = (g >> 6) + ki - 1, tx = (g & 63) + kj - 1;
        uint4 v = make_uint4(0u, 0u, 0u, 0u);
        if ((unsigned)ty < 64u && (unsigned)tx < 64u) {
          const u16* src = (mat == 0) ? A0h : (mat == 1) ? A0l : (mat == 2) ? B0h : B0l;
          v = *(const uint4*)(&src[(((size_t)(ty << 6) + tx) << 6) + (hh << 5) + (cs << 3)]);
        }
        u16* dst = (mat == 0) ? Ah : (mat == 1) ? Al : (mat == 2) ? Bh : Bl;
        *(uint4*)(&dst[row * 40 + (cs << 3)]) = v;
      }
      __syncthreads();
      short8 afh[4], afl[4], bfh[4], bfl[4];
#pragma unroll
      for (int i = 0; i < 4; ++i) {
        int ra = ((wl << 6) + (i << 4) + cc) * 40 + (q << 3);
        afh[i] = *(const short8*)(&Ah[ra]);
        afl[i] = *(const short8*)(&Al[ra]);
      }
#pragma unroll
      for (int j = 0; j < 4; ++j) {
        int rb = ((wm << 6) + (j << 4) + cc) * 40 + (q << 3);
        bfh[j] = *(const short8*)(&Bh[rb]);
        bfl[j] = *(const short8*)(&Bl[rb]);
      }
#pragma unroll
      for (int i = 0; i < 4; ++i)
#pragma unroll
        for (int j = 0; j < 4; ++j) {
          acc[i][j] = __builtin_amdgcn_mfma_f32_16x16x32_bf16(afh[i], bfl[j], acc[i][j], 0, 0, 0);
          acc[i][j] = __builtin_amdgcn_mfma_f32_16x16x32_bf16(afl[i], bfh[j], acc[i][j], 0, 0, 0);
          acc[i][j] = __builtin_amdgcn_mfma_f32_16x16x32_bf16(afh[i], bfh[j], acc[i][j], 0, 0, 0);
        }
    }
#pragma unroll
    for (int i = 0; i < 4; ++i) {
#pragma unroll
      for (int rg = 0; rg < 4; ++rg) {
        int l = row0 + (wl << 6) + (i << 4) + (q << 2) + rg;
        float sc = inv0b[l];
#pragma unroll
        for (int j = 0; j < 4; ++j) {
          float v = acc[i][j][rg] * sc;
          if (v > bval[j]) { bval[j] = v; bidx[j] = l; }
        }
      }
    }
  }

  __syncthreads();
  int slot = (wl << 2) + q;
#pragma unroll
  for (int j = 0; j < 4; ++j) {
    int col = (wm << 6) + (j << 4) + cc;
    lval[col * 8 + slot] = bval[j];
    lidx[col * 8 + slot] = bidx[j];
  }
  __syncthreads();
  if (t < 128) {
    float bv = -1e30f; int bi = 0x7FFFFFFF;
    for (int s = 0; s < 8; ++s) {
      float v = lval[t * 8 + s]; int id = lidx[t * 8 + s];
      if (v > bv || (v == bv && id < bi)) { bv = v; bi = id; }
    }
    size_t o = (size_t)(((b << 3) + lt) << 12) + (mt << 7) + t;
    pval[o] = bv; pidx[o] = bi;
  }
}

// ---------------- K5: reduce partials -> S, argmax
__global__ __launch_bounds__(256) void reduce_kernel(const float* __restrict__ pval,
    const int* __restrict__ pidx, const float* __restrict__ inv1,
    float* __restrict__ S, int* __restrict__ arg)
{
  int tid = blockIdx.x * 256 + threadIdx.x;
  int b = tid >> 12, m = tid & 4095;
  float bv = -1e30f; int bi = 0x7FFFFFFF;
  for (int lt = 0; lt < 8; ++lt) {
    size_t o = (size_t)(((b << 3) + lt) << 12) + m;
    float v = pval[o]; int id = pidx[o];
    if (v > bv || (v == bv && id < bi)) { bv = v; bi = id; }
  }
  S[tid] = bv * inv1[tid];
  arg[tid] = ((unsigned)bi < 4096u) ? bi : 0;
}

// ---------------- K6: T = fold3(gather(f0_unfold, arg))/9 -> NHWC fp32 (no transpose)
__global__ __launch_bounds__(256) void tgather_kernel(const float* __restrict__ f0,
    const int* __restrict__ arg, float* __restrict__ T)
{
  __shared__ int a3[192];
  int y = blockIdx.x, b = blockIdx.y, t = threadIdx.x;
  if (t < 192) {
    int r = t >> 6, xx = t & 63;
    int yy = y + r - 1;
    a3[t] = (yy >= 0 && yy < 64) ? arg[(b << 12) + (yy << 6) + xx] : 0;
  }
  __syncthreads();
  int c = t & 63, pg = t >> 6;
  for (int it = 0; it < 16; ++it) {
    int px = pg + (it << 2);
    float sum = 0.f;
#pragma unroll
    for (int ki = 0; ki < 3; ++ki) {
      int yn = y + 1 - ki;
      if (yn < 0 || yn >= 64) continue;
#pragma unroll
      for (int kj = 0; kj < 3; ++kj) {
        int xn = px + 1 - kj;
        if (xn < 0 || xn >= 64) continue;
        int p = a3[((2 - ki) << 6) + xn];
        int sy = (p >> 6) + ki - 1, sx = (p & 63) + kj - 1;
        if (sy >= 0 && sy < 64 && sx >= 0 && sx < 64)
          sum += f0[((((size_t)b << 12) + (sy << 6) + sx) << 6) + c];
      }
    }
    T[((((size_t)b << 12) + (y << 6) + px)) * 64 + c] = sum * (1.f / 9.f);
  }
}

// ---------------- K7: implicit-GEMM MFMA conv, NHWC fp32 act, pre-split bf16 weights.
// Tile = one image row (64 px) x 64 cout; 4 waves: wh2 = pixel half (32), wm = cout half (32).
// dm=1: A = c1-c0 on the fly (conv1). CINCH=4: cin>=64 from in1 (conv5 concat).
template<int KS, int CINCH>
__global__ __launch_bounds__(256) void conv_mfma(const float* __restrict__ in0,
    const float* __restrict__ in1, const u16* __restrict__ whp, const u16* __restrict__ wlp,
    const float* __restrict__ bias, float* __restrict__ outp,
    const float* __restrict__ res, int dorelu, int dm)
{
  constexpr int P = KS / 2;
  constexpr int CIN = CINCH * 32;
  __shared__ __align__(16) u16 Ah[64 * 40], Al[64 * 40];
  __shared__ __align__(16) u16 Bh[64 * 40], Bl[64 * 40];
  int tile = blockIdx.x, b = blockIdx.y;       // tile = image row y
  int t = threadIdx.x;
  int lane = t & 63, w = t >> 6;
  int wh2 = w >> 1, wm = w & 1;
  int cc = lane & 15, q = lane >> 4;
  const size_t abase = (size_t)b << 12;
  f32x4 acc[2][2];
#pragma unroll
  for (int i = 0; i < 2; ++i)
#pragma unroll
    for (int j = 0; j < 2; ++j) acc[i][j] = (f32x4){0.f, 0.f, 0.f, 0.f};

  for (int tap = 0; tap < KS * KS; ++tap) {
    int ki = tap / KS, kj = tap - ki * KS;
    int iy = tile + ki - P;                    // y uniform across the tile
    for (int kk = 0; kk < CINCH; ++kk) {
      __syncthreads();
      {  // stage A: 64 rows x 32 cin, hi/lo; 256 items (1/thread)
        int row = t >> 2, cs = t & 3;
        int ix = row + kj - P;
        float v[8];
#pragma unroll
        for (int e = 0; e < 8; ++e) v[e] = 0.f;
        if ((unsigned)iy < 64u && (unsigned)ix < 64u) {
          size_t base = (abase + (iy << 6) + ix) << 6;
          int cg = kk * 32 + (cs << 3);
          if (dm) {
            float4 a0 = *(const float4*)(in0 + base + cg);
            float4 a1 = *(const float4*)(in0 + base + cg + 4);
            float4 b0 = *(const float4*)(in1 + base + cg);
            float4 b1 = *(const float4*)(in1 + base + cg + 4);
            v[0] = b0.x - a0.x; v[1] = b0.y - a0.y; v[2] = b0.z - a0.z; v[3] = b0.w - a0.w;
            v[4] = b1.x - a1.x; v[5] = b1.y - a1.y; v[6] = b1.z - a1.z; v[7] = b1.w - a1.w;
          } else {
            const float* sp = (CINCH == 4 && cg >= 64) ? (in1 + base + (cg - 64))
                                                       : (in0 + base + cg);
            float4 a0 = *(const float4*)sp;
            float4 a1 = *(const float4*)(sp + 4);
            v[0] = a0.x; v[1] = a0.y; v[2] = a0.z; v[3] = a0.w;
            v[4] = a1.x; v[5] = a1.y; v[6] = a1.z; v[7] = a1.w;
          }
        }
        uint4 uh, ul;
        bsplit2(v[0], v[1], uh.x, ul.x);
        bsplit2(v[2], v[3], uh.y, ul.y);
        bsplit2(v[4], v[5], uh.z, ul.z);
        bsplit2(v[6], v[7], uh.w, ul.w);
        *(uint4*)&Ah[row * 40 + (cs << 3)] = uh;
        *(uint4*)&Al[row * 40 + (cs << 3)] = ul;
      }
#pragma unroll
      for (int it = 0; it < 2; ++it) {  // stage B: 64 couts x 32 cin, h then l
        int row = t >> 2, cs = t & 3;
        const u16* wsrc = it ? wlp : whp;
        uint4 vv = *(const uint4*)&wsrc[(size_t)(tap * 64 + row) * CIN + kk * 32 + (cs << 3)];
        u16* dst = it ? Bl : Bh;
        *(uint4*)&dst[row * 40 + (cs << 3)] = vv;
      }
      __syncthreads();
      short8 afh[2], afl[2], bfh[2], bfl[2];
#pragma unroll
      for (int i = 0; i < 2; ++i) {
        int ra = ((wh2 << 5) + (i << 4) + cc) * 40 + (q << 3);
        afh[i] = *(const short8*)&Ah[ra];
        afl[i] = *(const short8*)&Al[ra];
      }
#pragma unroll
      for (int j = 0; j < 2; ++j) {
        int rb = ((wm << 5) + (j << 4) + cc) * 40 + (q << 3);
        bfh[j] = *(const short8*)&Bh[rb];
        bfl[j] = *(const short8*)&Bl[rb];
      }
#pragma unroll
      for (int i = 0; i < 2; ++i)
#pragma unroll
        for (int j = 0; j < 2; ++j) {
          acc[i][j] = __builtin_amdgcn_mfma_f32_16x16x32_bf16(afh[i], bfl[j], acc[i][j], 0, 0, 0);
          acc[i][j] = __builtin_amdgcn_mfma_f32_16x16x32_bf16(afl[i], bfh[j], acc[i][j], 0, 0, 0);
          acc[i][j] = __builtin_amdgcn_mfma_f32_16x16x32_bf16(afh[i], bfh[j], acc[i][j], 0, 0, 0);
        }
    }
  }
  // epilogue: C/D row (pixel) = q*4+reg, col (cout) = cc
#pragma unroll
  for (int i = 0; i < 2; ++i)
#pragma unroll
    for (int rg = 0; rg < 4; ++rg) {
      int p = (tile << 6) + (wh2 << 5) + (i << 4) + (q << 2) + rg;
#pragma unroll
      for (int j = 0; j < 2; ++j) {
        int cout = (wm << 5) + (j << 4) + cc;
        float v = acc[i][j][rg] + bias[cout];
        if (dorelu) v = fmaxf(v, 0.f);
        size_t oi = ((abase + p) << 6) + cout;
        if (res) v += res[oi];
        outp[oi] = v;
      }
    }
}

// ---------------- K8: out = dcf + xs*S (all NHWC = output NLC layout), elementwise
__global__ __launch_bounds__(256) void final_kernel(const float* __restrict__ dcf,
    const float* __restrict__ xs, const float* __restrict__ S, float* __restrict__ out)
{
  int tid = blockIdx.x * 256 + threadIdx.x;    // grid 4096 -> 1,048,576
  out[tid] = dcf[tid] + xs[tid] * S[tid >> 6];
}

extern "C" void kernel_launch(void* const* d_in, const int* in_sizes, int n_in,
                              void* d_out, int out_size, void* d_ws, size_t ws_size,
                              hipStream_t stream)
{
  (void)in_sizes; (void)n_in; (void)out_size; (void)ws_size;
  const float* c0     = (const float*)d_in[0];
  const float* f0     = (const float*)d_in[1];
  const float* c1     = (const float*)d_in[2];
  const float* head_w = (const float*)d_in[3];
  const float* head_b = (const float*)d_in[4];
  const float* rb_w1  = (const float*)d_in[5];
  const float* rb_b1  = (const float*)d_in[6];
  const float* rb_w2  = (const float*)d_in[7];
  const float* rb_b2  = (const float*)d_in[8];
  const float* tail_w = (const float*)d_in[9];
  const float* tail_b = (const float*)d_in[10];
  const float* sq_w   = (const float*)d_in[11];
  const float* sq_b   = (const float*)d_in[12];
  float* out = (float*)d_out;
  char* ws = (char*)d_ws;

  // ---- layout: 15,958,016 B total ----
  const size_t OFF_SS0  = 0;
  const size_t OFF_SS1  = 65536;
  const size_t OFF_INV0 = 131072;
  const size_t OFF_INV1 = 196608;
  const size_t OFF_S    = 262144;
  const size_t OFF_ARG  = 327680;
  const size_t OFF_PVAL = 393216;       // 512 KB
  const size_t OFF_PIDX = 917504;       // 512 KB
  const size_t OFF_WHH  = 1441792;      // head  hi 204800
  const size_t OFF_WHL  = 1646592;      // head  lo 204800
  const size_t OFF_W1H  = 1851392;      // rb1   hi 73728
  const size_t OFF_W1L  = 1925120;
  const size_t OFF_W2H  = 1998848;      // rb2   hi 73728
  const size_t OFF_W2L  = 2072576;
  const size_t OFF_WTH  = 2146304;      // tail  hi 204800
  const size_t OFF_WTL  = 2351104;
  const size_t OFF_WSH  = 2555904;      // sq    hi 409600
  const size_t OFF_WSL  = 2965504;
  const size_t OFF_SA   = 3375104;      // 4 MB: c0h/c0l -> x1 -> T
  const size_t OFF_SB   = 7569408;      // 4 MB: c1h/c1l -> hb -> dcf
  const size_t OFF_SC   = 11763712;     // 4 MB: xb -> xs

  float* ss0  = (float*)(ws + OFF_SS0);
  float* ss1  = (float*)(ws + OFF_SS1);
  float* inv0 = (float*)(ws + OFF_INV0);
  float* inv1 = (float*)(ws + OFF_INV1);
  float* Sbuf = (float*)(ws + OFF_S);
  int*   argb = (int*)(ws + OFF_ARG);
  float* pval = (float*)(ws + OFF_PVAL);
  int*   pidx = (int*)(ws + OFF_PIDX);
  u16* whh = (u16*)(ws + OFF_WHH); u16* whl = (u16*)(ws + OFF_WHL);
  u16* w1h = (u16*)(ws + OFF_W1H); u16* w1l = (u16*)(ws + OFF_W1L);
  u16* w2h = (u16*)(ws + OFF_W2H); u16* w2l = (u16*)(ws + OFF_W2L);
  u16* wth = (u16*)(ws + OFF_WTH); u16* wtl = (u16*)(ws + OFF_WTL);
  u16* wsh = (u16*)(ws + OFF_WSH); u16* wsl = (u16*)(ws + OFF_WSL);
  u16* c0h = (u16*)(ws + OFF_SA); u16* c0l = (u16*)(ws + OFF_SA + 2097152);
  u16* c1h = (u16*)(ws + OFF_SB); u16* c1l = (u16*)(ws + OFF_SB + 2097152);
  float* x1  = (float*)(ws + OFF_SA);
  float* Tb  = (float*)(ws + OFF_SA);
  float* hb  = (float*)(ws + OFF_SB);
  float* dcf = (float*)(ws + OFF_SB);
  float* xb  = (float*)(ws + OFF_SC);
  float* xsb = (float*)(ws + OFF_SC);

  dim3 b256(256);
  prep_ss<<<dim3(64), b256, 0, stream>>>(c0, c1, ss0, ss1);
  norm_kernel<<<dim3(64), b256, 0, stream>>>(ss0, ss1, inv0, inv1);
  split_kernel<<<dim3(4096), b256, 0, stream>>>(c0, c1, c0h, c0l, c1h, c1l);
  wprep<<<dim3(400), b256, 0, stream>>>(head_w, whh, whl, 64, 25, 102400);
  wprep<<<dim3(144), b256, 0, stream>>>(rb_w1 + 110592, w1h, w1l, 64, 9, 36864);
  wprep<<<dim3(144), b256, 0, stream>>>(rb_w2 + 110592, w2h, w2l, 64, 9, 36864);
  wprep<<<dim3(400), b256, 0, stream>>>(tail_w, wth, wtl, 64, 25, 102400);
  wprep<<<dim3(800), b256, 0, stream>>>(sq_w, wsh, wsl, 128, 25, 204800);

  corr_mfma<<<dim3(32, 8, BATCH), b256, 0, stream>>>(c0h, c0l, c1h, c1l, inv0, pval, pidx);
  reduce_kernel<<<dim3(64), b256, 0, stream>>>(pval, pidx, inv1, Sbuf, argb);

  // conv stack (only residual block 3 affects output); all NHWC
  dim3 cgrid(64, BATCH);
  conv_mfma<5, 2><<<cgrid, b256, 0, stream>>>(c0, c1, whh, whl, head_b, x1, nullptr, 0, 1);
  conv_mfma<3, 2><<<cgrid, b256, 0, stream>>>(x1, nullptr, w1h, w1l, rb_b1 + 192, hb, nullptr, 1, 0);
  conv_mfma<3, 2><<<cgrid, b256, 0, stream>>>(hb, nullptr, w2h, w2l, rb_b2 + 192, xb, x1, 0, 0);
  conv_mfma<5, 2><<<cgrid, b256, 0, stream>>>(xb, nullptr, wth, wtl, tail_b, dcf, x1, 0, 0);

  tgather_kernel<<<dim3(64, BATCH), b256, 0, stream>>>(f0, argb, Tb);   // x1 dead after conv4
  conv_mfma<5, 4><<<cgrid, b256, 0, stream>>>(dcf, Tb, wsh, wsl, sq_b, xsb, nullptr, 0, 0);

  final_kernel<<<dim3(4096), b256, 0, stream>>>(dcf, xsb, Sbuf, out);
}